// Round 9
// baseline (258.169 us; speedup 1.0000x reference)
//
#include <hip/hip_runtime.h>
#include <float.h>
#include <math.h>

#define K_CODES 1024
#define ED 64
#define NTOK 131072
#define EPS 4e-4f   // flag band; approx-vs-exact bound ~7e-5 -> 6x margin

typedef __attribute__((ext_vector_type(8)))  short short8;   // 8 bf16 (4 VGPRs)
typedef __attribute__((ext_vector_type(16))) float float16;  // MFMA 32x32 acc

// ---------------------------------------------------------------------------
// NUMERICS OF THE EXACT PATH ARE FROZEN (0 flips across all passing rounds):
//  - zsq / e_sq: numpy pairwise_sum n=64 (8 accs strided 8, mul+add no fma,
//    combine ((r0+r1)+(r2+r3))+((r4+r5)+(r6+r7))), contract(off).
//  - dot(z,e): single sequential fmaf chain over d=0..63.
//  - d2 = fmaf(-2,dot,zsq) + e_sq.
//  - argmin: first index wins (lexicographic (value,index) updates).
//
// Round-15 (this file): byte-identical resubmit of round-14 (container died
// to infra twice, no kernel signal; full audit of the new ticket/fence
// surface found no hang or ordering defect -- same precedent as rounds 2/3).
//  (a) vq_final FUSED into vq_main via last-block ticket (device-scope
//      atomic after each block's epilogue; ONLY the last-arriving block
//      computes the scalars -- no spin wait, no dispatch-order assumption).
//      Removes a 1-block launch and its stream gap. Cross-XCD visibility via
//      __threadfence + __hip_atomic AGENT-scope ops (G16).
//  (b) vq_codes spread to 16 blocks x 64 (was 4 CUs doing all code prep).
//  (c) R phase: ALL 4 waves, 4 lanes/token (was waves 0-1 only -- half the
//      block idled at a barrier). Per-lane 8-tile scan, quad merge via
//      __shfl_xor(1,2): fminf tree == exact frozen min; cand0 merged
//      lo-sub-first == first-in-ct-order; rescore lex (d2,idx) fold is a
//      total order -> bit-identical bsel.
//  (d) E's z float4s prefetched into regs BEFORE the R barrier (independent
//      loads hidden under R; compiler won't hoist globals across barriers).
// S / M phases verbatim from round-7 (passing, no-spill, VGPR 68).
// ---------------------------------------------------------------------------

static __device__ __forceinline__ unsigned short f2bf(float x) {  // RNE
    unsigned u = __float_as_uint(x);
    u += 0x7fffu + ((u >> 16) & 1u);
    return (unsigned short)(u >> 16);
}
static __device__ __forceinline__ float bf2f(unsigned short h) {
    return __uint_as_float(((unsigned)h) << 16);
}

// ---------------------------------------------------------------------------
// code pre: 16 blocks x 64 = 1024 codes. e_sq (frozen pairwise) + e bf16
// hi/lo fragments + zero counts shards / sse partials / ticket.
// frag[(tile*8 + g)*32 + (code&31)], g = d/8.
// ---------------------------------------------------------------------------
__global__ __launch_bounds__(64) void vq_codes(const float* __restrict__ cb,
                                               float* __restrict__ e_sq,
                                               short8* __restrict__ efH,
                                               short8* __restrict__ efL,
                                               unsigned int* __restrict__ counts,
                                               float* __restrict__ sse_part,
                                               unsigned int* __restrict__ done)
{
#pragma clang fp contract(off)
    const int k = blockIdx.x * 64 + threadIdx.x;    // 0..1023
    const float4* ep = (const float4*)(cb + (size_t)k * ED);
    const int m = k & 31, ct = k >> 5;
    float r[8];
#pragma unroll
    for (int g = 0; g < 8; ++g) {
        float4 a = ep[2 * g], b = ep[2 * g + 1];
        float v[8] = {a.x, a.y, a.z, a.w, b.x, b.y, b.z, b.w};
        short8 hv, lv;
#pragma unroll
        for (int j = 0; j < 8; ++j) {
            unsigned short hb = f2bf(v[j]);
            hv[j] = (short)hb;
            lv[j] = (short)f2bf(v[j] - bf2f(hb));
            const float sq = v[j] * v[j];          // frozen pairwise e_sq
            r[j] = g ? (r[j] + sq) : sq;
        }
        efH[(ct * 8 + g) * 32 + m] = hv;
        efL[(ct * 8 + g) * 32 + m] = lv;
    }
    e_sq[k] = ((r[0] + r[1]) + (r[2] + r[3])) + ((r[4] + r[5]) + (r[6] + r[7]));
    counts[k]        = 0u;   // 4 shards
    counts[k + 1024] = 0u;
    counts[k + 2048] = 0u;
    counts[k + 3072] = 0u;
    if (k < 64) sse_part[k] = 0.f;
    if (k == 0) *done = 0u;
}

// ---------------------------------------------------------------------------
// Frozen exact rescore of code (cc): single sequential fmaf chain d=0..63,
// d2 = fmaf(-2,dot,zsq) + e_sq; lexicographic (d2, idx) update.
#define RESCORE(cc)                                                          \
    do {                                                                     \
        const int c_ = (cc);                                                 \
        const float4* e4_ = (const float4*)(cb + (size_t)c_ * ED);           \
        float a_ = 0.f;                                                      \
        _Pragma("unroll")                                                    \
        for (int jj_ = 0; jj_ < 16; ++jj_) {                                 \
            const float4 v_ = e4_[jj_];                                      \
            a_ = fmaf(zr[4 * jj_ + 0], v_.x, a_);                            \
            a_ = fmaf(zr[4 * jj_ + 1], v_.y, a_);                            \
            a_ = fmaf(zr[4 * jj_ + 2], v_.z, a_);                            \
            a_ = fmaf(zr[4 * jj_ + 3], v_.w, a_);                            \
        }                                                                    \
        const float d2_ = fmaf(-2.f, a_, zsq) + e_sq[c_];                    \
        if (d2_ < best || (d2_ == best && c_ < bi)) { best = d2_; bi = c_; } \
    } while (0)

// ---------------------------------------------------------------------------
// fused main: 64 tokens/block, 2048 blocks, 4 waves.
//  S: wave wv stages z frags for groups {2wv,2wv+1}, lane=token.
//  M: wave owns tiles {g*8+wv*2, +1} per group (4 groups, unrolled);
//     tree-reduced bit-identical (max,argmax-first,exact-2nd) -> LDS sel.
//  R: ALL waves, 4 lanes/token (sub = tid&3 owns tiles sub*8..sub*8+7);
//     quad merge via shfl_xor(1,2); rare rescore recomputes frozen zsq.
//  E: coalesced epilogue with pre-barrier z prefetch; atomics.
//  F: last-block ticket -> entropy/loss scalars (fused vq_final).
// ---------------------------------------------------------------------------
__global__ __launch_bounds__(256, 3) void vq_main(const float* __restrict__ z_e,
                                                  const float* __restrict__ cb,
                                                  const float* __restrict__ e_sq,
                                                  const short8* __restrict__ efH,
                                                  const short8* __restrict__ efL,
                                                  float* __restrict__ out_zq,
                                                  float* __restrict__ out_idx,
                                                  float* __restrict__ out_sc,
                                                  unsigned int* __restrict__ counts,
                                                  float* __restrict__ sse_part,
                                                  unsigned int* __restrict__ done)
{
#pragma clang fp contract(off)
    __shared__ short8 s_zfh[512];        // [2 tt][8 g][32 n]   8 KB
    __shared__ short8 s_zfl[512];        //                     8 KB
    __shared__ float2 s_sel[32 * 64];    // [tile][token]      16 KB
    __shared__ int    s_bi[64];
    __shared__ float  s_wsse[4];
    __shared__ float  s_red[256];        // last-block reduce scratch
    __shared__ int    s_last;

    const int tid = threadIdx.x;
    const int wv = tid >> 6, lane = tid & 63;
    const int h = lane >> 5, ml = lane & 31;
    const int t0 = blockIdx.x * 64;

    // ---- S: all waves stage; wave wv owns groups {2wv, 2wv+1} ------------
    {
        const float4* zp = (const float4*)(z_e + (size_t)(t0 + lane) * ED);
        const int n = lane & 31, ttl = lane >> 5;
#pragma unroll
        for (int gg = 0; gg < 2; ++gg) {
            const int g = wv * 2 + gg;
            float4 a = zp[2 * g], b = zp[2 * g + 1];
            float v[8] = {a.x, a.y, a.z, a.w, b.x, b.y, b.z, b.w};
            short8 hv, lv;
#pragma unroll
            for (int j = 0; j < 8; ++j) {
                unsigned short hb = f2bf(v[j]);    // bit-identical split
                hv[j] = (short)hb;
                lv[j] = (short)f2bf(v[j] - bf2f(hb));
            }
            s_zfh[(ttl * 8 + g) * 32 + n] = hv;
            s_zfl[(ttl * 8 + g) * 32 + n] = lv;
        }
    }
    __syncthreads();

    // ---- M: score all 32 code tiles (4 groups x 2 tiles/wave) ------------
#pragma unroll
    for (int g = 0; g < 4; ++g) {
        short8 ea[2][4], eb[2][4];                 // A-frags for this group
#pragma unroll
        for (int mt = 0; mt < 2; ++mt) {
            const int ct = g * 8 + wv * 2 + mt;
#pragma unroll
            for (int q = 0; q < 4; ++q) {
                const int idx = (ct * 8 + q * 2 + h) * 32 + ml;
                ea[mt][q] = efH[idx];
                eb[mt][q] = efL[idx];
            }
        }
#pragma unroll
        for (int it = 0; it < 2; ++it) {
            float16 acc0 = {}, acc1 = {};
#pragma unroll
            for (int q = 0; q < 4; ++q) {
                const int idx = (it * 8 + q * 2 + h) * 32 + ml;
                const short8 zh = s_zfh[idx];
                const short8 zl = s_zfl[idx];
                acc0 = __builtin_amdgcn_mfma_f32_32x32x16_bf16(ea[0][q], zh, acc0, 0, 0, 0);
                acc1 = __builtin_amdgcn_mfma_f32_32x32x16_bf16(ea[1][q], zh, acc1, 0, 0, 0);
                acc0 = __builtin_amdgcn_mfma_f32_32x32x16_bf16(ea[0][q], zl, acc0, 0, 0, 0);
                acc1 = __builtin_amdgcn_mfma_f32_32x32x16_bf16(ea[1][q], zl, acc1, 0, 0, 0);
                acc0 = __builtin_amdgcn_mfma_f32_32x32x16_bf16(eb[0][q], zh, acc0, 0, 0, 0);
                acc1 = __builtin_amdgcn_mfma_f32_32x32x16_bf16(eb[1][q], zh, acc1, 0, 0, 0);
            }
#pragma unroll
            for (int mt = 0; mt < 2; ++mt) {
                const float16 acc = mt ? acc1 : acc0;
                // Tree reduce, rg-adjacent, keep-left-on-tie: bit-identical
                // (v1 = max, i1 = mrow of FIRST max in rg order, v2 = exact
                // 2nd-largest via max(min(maxA,maxB), v2A, v2B)).
                float tv1[8], tv2[8];
                int   ti[8];
#pragma unroll
                for (int p = 0; p < 8; ++p) {
                    const float a = acc[2 * p], b = acc[2 * p + 1];
                    const int ia = ((2 * p) & 3) + 8 * ((2 * p) >> 2) + 4 * h;
                    const int ib = ((2 * p + 1) & 3) + 8 * ((2 * p + 1) >> 2) + 4 * h;
                    const bool gt = b > a;
                    tv1[p] = gt ? b : a;
                    ti[p]  = gt ? ib : ia;
                    tv2[p] = gt ? a : b;
                }
#pragma unroll
                for (int s = 4; s >= 1; s >>= 1) {
#pragma unroll
                    for (int p = 0; p < s; ++p) {
                        const float av1 = tv1[2 * p], bv1 = tv1[2 * p + 1];
                        const bool gt = bv1 > av1;
                        const float inner = gt ? av1 : bv1;
                        tv1[p] = gt ? bv1 : av1;
                        ti[p]  = gt ? ti[2 * p + 1] : ti[2 * p];
                        tv2[p] = fmaxf(fmaxf(tv2[2 * p], tv2[2 * p + 1]), inner);
                    }
                }
                float v1 = tv1[0], v2 = tv2[0];
                int i1 = ti[0];
                const float o1 = __shfl_xor(v1, 32);
                const float o2 = __shfl_xor(v2, 32);
                const int   oi = __shfl_xor(i1, 32);
                const float lo = fminf(v1, o1);
                if (o1 > v1) { v1 = o1; i1 = oi; }
                v2 = fmaxf(lo, fmaxf(v2, o2));      // exact 2nd-largest merge
                if (lane < 32) {
                    const unsigned bits = (__float_as_uint(-2.f * v1) & ~31u) | (unsigned)i1;
                    float2 o;
                    o.x = __uint_as_float(bits);    // bit-identical tA
                    o.y = -2.f * v2;                // bit-identical tB
                    s_sel[(g * 8 + wv * 2 + mt) * 64 + it * 32 + lane] = o;
                }
            }
        }
    }

    // ---- E-prefetch: z float4s into regs BEFORE the barrier --------------
    const float4* z4  = (const float4*)z_e + (size_t)t0 * 16;
    float4 zv[4];
#pragma unroll
    for (int p = 0; p < 4; ++p) zv[p] = z4[p * 256 + tid];
    __syncthreads();

    // ---- R: selection, ALL waves, 4 lanes/token --------------------------
    {
        const int tls = tid >> 2;              // token slot 0..63
        const int sub = tid & 3;               // owns tiles sub*8 .. sub*8+7
        const int t = t0 + tls;

        float av[8], bv[8];
        float m = FLT_MAX;
#pragma unroll
        for (int i = 0; i < 8; ++i) {
            const float2 p = s_sel[(sub * 8 + i) * 64 + tls];
            av[i] = p.x; bv[i] = p.y;
            m = fminf(m, av[i]);
        }
        m = fminf(m, __shfl_xor(m, 1));        // exact fminf tree == min32
        m = fminf(m, __shfl_xor(m, 2));
        const float thr = m + EPS;

        unsigned band8 = 0u, full8 = 0u;
        int cand0 = 0, nb = 0;
#pragma unroll
        for (int i = 0; i < 8; ++i) {
            if (av[i] <= thr) {
                if (nb == 0)
                    cand0 = (sub * 8 + i) * 32 + (int)(__float_as_uint(av[i]) & 31u);
                ++nb;
                band8 |= (1u << i);
                if (bv[i] <= thr) full8 |= (1u << i);
            }
        }
        // merge (nb, first-in-ct-order cand0, full-any) across the quad:
        // lo-sub partition wins when nonempty == frozen first-tile order.
        int fullany = (full8 != 0u);
        {
            int nb_o = __shfl_xor(nb, 1);
            int c0_o = __shfl_xor(cand0, 1);
            int fa_o = __shfl_xor(fullany, 1);
            cand0 = ((sub & 1) == 0) ? (nb ? cand0 : c0_o) : (nb_o ? c0_o : cand0);
            nb += nb_o; fullany |= fa_o;
            nb_o = __shfl_xor(nb, 2);
            c0_o = __shfl_xor(cand0, 2);
            fa_o = __shfl_xor(fullany, 2);
            cand0 = ((sub & 2) == 0) ? (nb ? cand0 : c0_o) : (nb_o ? c0_o : cand0);
            nb += nb_o; fullany |= fa_o;
        }

        int bsel;
        if (nb == 1 && !fullany) {
            bsel = cand0;              // unambiguous: band proves exact argmin
        } else {
            // Rare path (quad-uniform branch): each lane rescores its own
            // in-band tiles with the frozen chain; lex merge across quad.
            const float4* zp = (const float4*)(z_e + (size_t)t * ED);
            float zr[ED];
#pragma unroll
            for (int i = 0; i < 16; ++i) {
                const float4 v = zp[i];
                zr[4 * i + 0] = v.x; zr[4 * i + 1] = v.y;
                zr[4 * i + 2] = v.z; zr[4 * i + 3] = v.w;
            }
            // frozen zsq: numpy pairwise n=64, 8 accs strided 8, mul+add
            float r[8];
#pragma unroll
            for (int g2 = 0; g2 < 8; ++g2) {
#pragma unroll
                for (int j = 0; j < 8; ++j) {
                    const float sq = zr[g2 * 8 + j] * zr[g2 * 8 + j];
                    r[j] = g2 ? (r[j] + sq) : sq;
                }
            }
            const float zsq = ((r[0] + r[1]) + (r[2] + r[3])) + ((r[4] + r[5]) + (r[6] + r[7]));
            float best = FLT_MAX;
            int bi = 0;
            unsigned rem = band8;
            while (rem) {
                const int i = __ffs(rem) - 1;
                rem &= rem - 1;
                const int ct = sub * 8 + i;
                if (full8 & (1u << i)) {
                    for (int j = 0; j < 32; ++j) RESCORE(ct * 32 + j);
                } else {
                    RESCORE(ct * 32 + (int)(__float_as_uint(av[i]) & 31u));
                }
            }
#pragma unroll
            for (int d = 1; d <= 2; d <<= 1) {
                const float ob  = __shfl_xor(best, d);
                const int   obi = __shfl_xor(bi, d);
                if (ob < best || (ob == best && obi < bi)) { best = ob; bi = obi; }
            }
            bsel = bi;
        }

        if (sub == 0) {
            s_bi[tls] = bsel;
            out_idx[t] = (float)bsel;
            atomicAdd(&counts[(blockIdx.x & 3) * K_CODES + bsel], 1u);  // sharded
        }
    }
    __syncthreads();

    // ---- E: epilogue, flat-contiguous (thread <-> float4), z pre-loaded --
    float4* o4 = (float4*)out_zq + (size_t)t0 * 16;
    const float4* eq4 = (const float4*)cb;
    float lsse = 0.f;
#pragma unroll
    for (int p = 0; p < 4; ++p) {
        const int f = p * 256 + tid;               // 0..1023 float4s
        const int bq = s_bi[f >> 4];
        const float4 q = eq4[(size_t)bq * 16 + (f & 15)];
        o4[f] = q;
        float dx = q.x - zv[p].x; lsse = fmaf(dx, dx, lsse);
        float dy = q.y - zv[p].y; lsse = fmaf(dy, dy, lsse);
        float dz = q.z - zv[p].z; lsse = fmaf(dz, dz, lsse);
        float dw = q.w - zv[p].w; lsse = fmaf(dw, dw, lsse);
    }
#pragma unroll
    for (int off = 32; off > 0; off >>= 1)
        lsse += __shfl_down(lsse, off, 64);
    if (lane == 0) s_wsse[wv] = lsse;
    __syncthreads();
    if (tid == 0)
        atomicAdd(&sse_part[blockIdx.x & 63],
                  (s_wsse[0] + s_wsse[1]) + (s_wsse[2] + s_wsse[3]));

    // ---- F: last-block ticket -> fused final scalars ---------------------
    if (tid == 0) {
        __threadfence();                           // order our atomics
        const unsigned tk = __hip_atomic_fetch_add(done, 1u, __ATOMIC_ACQ_REL,
                                                   __HIP_MEMORY_SCOPE_AGENT);
        s_last = (tk == (unsigned)(gridDim.x - 1)) ? 1 : 0;
    }
    __syncthreads();
    if (s_last) {
        float part = 0.f;
#pragma unroll
        for (int j = 0; j < 4; ++j) {
            const int i = tid + j * 256;           // code 0..1023
            unsigned cu = 0;
#pragma unroll
            for (int sd = 0; sd < 4; ++sd)
                cu += __hip_atomic_load(&counts[sd * K_CODES + i],
                                        __ATOMIC_RELAXED, __HIP_MEMORY_SCOPE_AGENT);
            const float p = (float)cu / (float)NTOK + 1e-10f;
            part += p * logf(p);
        }
        s_red[tid] = part;
        __syncthreads();
        for (int s = 128; s > 0; s >>= 1) {
            if (tid < s) s_red[tid] += s_red[tid + s];
            __syncthreads();
        }
        if (tid == 0) {
            const float entropy = -s_red[0];
            float ssum = 0.f;
            for (int k2 = 0; k2 < 64; ++k2)
                ssum += __hip_atomic_load(&sse_part[k2],
                                          __ATOMIC_RELAXED, __HIP_MEMORY_SCOPE_AGENT);
            const float cbl = ssum / ((float)NTOK * (float)ED);
            out_sc[0] = cbl;                                   // codebook_loss
            out_sc[1] = 0.25f * cbl;                           // commitment_loss
            out_sc[2] = -0.1f * (entropy / 6.93147180559945f); // entropy_loss
            out_sc[3] = expf(entropy);                         // perplexity
        }
    }
}

// ---------------------------------------------------------------------------
extern "C" void kernel_launch(void* const* d_in, const int* in_sizes, int n_in,
                              void* d_out, int out_size, void* d_ws, size_t ws_size,
                              hipStream_t stream)
{
    const float* z_e = (const float*)d_in[0];
    const float* cb  = (const float*)d_in[1];

    float* out   = (float*)d_out;
    float* o_zq  = out;                              // [131072,64]
    float* o_idx = out + (size_t)NTOK * ED;          // [131072] (as float)
    float* o_sc  = o_idx + NTOK;                     // 4 scalars

    char* ws = (char*)d_ws;
    float*        e_sq     = (float*)(ws);                   // 4 KB
    unsigned int* counts   = (unsigned int*)(ws + 4096);     // 16 KB (4 shards)
    float*        sse_part = (float*)(ws + 20480);           // 256 B
    unsigned int* done     = (unsigned int*)(ws + 20736);    // 4 B
    short8*       efH      = (short8*)(ws + 32768);          // 128 KB
    short8*       efL      = (short8*)(ws + 163840);         // 128 KB (ends 288 KB)

    vq_codes<<<16, 64, 0, stream>>>(cb, e_sq, efH, efL, counts, sse_part, done);
    vq_main <<<NTOK / 64, 256, 0, stream>>>(z_e, cb, e_sq, efH, efL,
                                            o_zq, o_idx, o_sc,
                                            counts, sse_part, done);
}

// Round 10
// 167.402 us; speedup vs baseline: 1.5422x; 1.5422x over previous
//
#include <hip/hip_runtime.h>
#include <float.h>
#include <math.h>

#define K_CODES 1024
#define ED 64
#define NTOK 131072
#define EPS 4e-4f   // flag band; approx-vs-exact bound ~7e-5 -> 6x margin

typedef __attribute__((ext_vector_type(8)))  short short8;   // 8 bf16 (4 VGPRs)
typedef __attribute__((ext_vector_type(16))) float float16;  // MFMA 32x32 acc

// ---------------------------------------------------------------------------
// NUMERICS OF THE EXACT PATH ARE FROZEN (0 flips across all passing rounds):
//  - zsq / e_sq: numpy pairwise_sum n=64 (8 accs strided 8, mul+add no fma,
//    combine ((r0+r1)+(r2+r3))+((r4+r5)+(r6+r7))), contract(off).
//  - dot(z,e): single sequential fmaf chain over d=0..63.
//  - d2 = fmaf(-2,dot,zsq) + e_sq.
//  - argmin: first index wins (lexicographic (value,index) updates).
//
// Round-16 (this file), from round-9 PMC (vq_main 200us, BANK_CONFLICT 786K,
// all pipes down) vs round-7 (vq_main 133us, conflicts 0):
//  - REVERTED: last-block ticket + __threadfence F fusion. Agent-scope
//    release on gfx950 implies L2 writeback (per-XCD L2 non-coherent);
//    2048 blocks x (wbl2 + inv) explained the uniform slowdown. vq_final
//    is a separate 1-block kernel again (round-7 verbatim).
//  - KEPT, defect removed: 4-lane/token R across ALL 4 waves (round-9 logic
//    verbatim, verified bit-identical) with s_sel PADDED to stride 65:
//    bank = (2*tls + 16*sub + 2*i) mod 32 -> <=2 lanes/bank (free, m136).
//    Round-9's stride-64 put all 4 sub-clusters on the same 16 banks
//    (tile*64*2 == 0 mod 32) -> 4-way conflict, 786K extra cycles.
//  - KEPT: E-phase z prefetch into regs before the R barrier (hides the
//    global reload latency under R; verified correct in round 9).
//  - KEPT: vq_codes spread over 16 blocks x 64.
// S / M phases and all selection numerics verbatim from round-7
// (__launch_bounds__(256,3), the proven no-spill point, VGPR 68).
// ---------------------------------------------------------------------------

static __device__ __forceinline__ unsigned short f2bf(float x) {  // RNE
    unsigned u = __float_as_uint(x);
    u += 0x7fffu + ((u >> 16) & 1u);
    return (unsigned short)(u >> 16);
}
static __device__ __forceinline__ float bf2f(unsigned short h) {
    return __uint_as_float(((unsigned)h) << 16);
}

// ---------------------------------------------------------------------------
// code pre: 16 blocks x 64 = 1024 codes. e_sq (frozen pairwise) + e bf16
// hi/lo fragments + zero counts shards / sse partials. Unchanged numerics.
// frag[(tile*8 + g)*32 + (code&31)], g = d/8.
// ---------------------------------------------------------------------------
__global__ __launch_bounds__(64) void vq_codes(const float* __restrict__ cb,
                                               float* __restrict__ e_sq,
                                               short8* __restrict__ efH,
                                               short8* __restrict__ efL,
                                               unsigned int* __restrict__ counts,
                                               float* __restrict__ sse_part)
{
#pragma clang fp contract(off)
    const int k = blockIdx.x * 64 + threadIdx.x;    // 0..1023
    const float4* ep = (const float4*)(cb + (size_t)k * ED);
    const int m = k & 31, ct = k >> 5;
    float r[8];
#pragma unroll
    for (int g = 0; g < 8; ++g) {
        float4 a = ep[2 * g], b = ep[2 * g + 1];
        float v[8] = {a.x, a.y, a.z, a.w, b.x, b.y, b.z, b.w};
        short8 hv, lv;
#pragma unroll
        for (int j = 0; j < 8; ++j) {
            unsigned short hb = f2bf(v[j]);
            hv[j] = (short)hb;
            lv[j] = (short)f2bf(v[j] - bf2f(hb));
            const float sq = v[j] * v[j];          // frozen pairwise e_sq
            r[j] = g ? (r[j] + sq) : sq;
        }
        efH[(ct * 8 + g) * 32 + m] = hv;
        efL[(ct * 8 + g) * 32 + m] = lv;
    }
    e_sq[k] = ((r[0] + r[1]) + (r[2] + r[3])) + ((r[4] + r[5]) + (r[6] + r[7]));
    counts[k]        = 0u;   // 4 shards
    counts[k + 1024] = 0u;
    counts[k + 2048] = 0u;
    counts[k + 3072] = 0u;
    if (k < 64) sse_part[k] = 0.f;
}

// ---------------------------------------------------------------------------
// Frozen exact rescore of code (cc): single sequential fmaf chain d=0..63,
// d2 = fmaf(-2,dot,zsq) + e_sq; lexicographic (d2, idx) update.
#define RESCORE(cc)                                                          \
    do {                                                                     \
        const int c_ = (cc);                                                 \
        const float4* e4_ = (const float4*)(cb + (size_t)c_ * ED);           \
        float a_ = 0.f;                                                      \
        _Pragma("unroll")                                                    \
        for (int jj_ = 0; jj_ < 16; ++jj_) {                                 \
            const float4 v_ = e4_[jj_];                                      \
            a_ = fmaf(zr[4 * jj_ + 0], v_.x, a_);                            \
            a_ = fmaf(zr[4 * jj_ + 1], v_.y, a_);                            \
            a_ = fmaf(zr[4 * jj_ + 2], v_.z, a_);                            \
            a_ = fmaf(zr[4 * jj_ + 3], v_.w, a_);                            \
        }                                                                    \
        const float d2_ = fmaf(-2.f, a_, zsq) + e_sq[c_];                    \
        if (d2_ < best || (d2_ == best && c_ < bi)) { best = d2_; bi = c_; } \
    } while (0)

#define SEL_STRIDE 65   // padded: bank = (2*tls + 16*sub + 2*i) mod 32

// ---------------------------------------------------------------------------
// fused main: 64 tokens/block, 2048 blocks, 4 waves.
//  S: wave wv stages z frags for groups {2wv,2wv+1}, lane=token.
//  M: wave owns tiles {g*8+wv*2, +1} per group (4 groups, unrolled);
//     tree-reduced bit-identical (max,argmax-first,exact-2nd) -> LDS sel.
//  R: ALL waves, 4 lanes/token (sub = tid&3 owns tiles sub*8..sub*8+7);
//     quad merge via shfl_xor(1,2); rare rescore recomputes frozen zsq.
//  E: coalesced epilogue; z pre-fetched into regs before the R barrier.
// ---------------------------------------------------------------------------
__global__ __launch_bounds__(256, 3) void vq_main(const float* __restrict__ z_e,
                                                  const float* __restrict__ cb,
                                                  const float* __restrict__ e_sq,
                                                  const short8* __restrict__ efH,
                                                  const short8* __restrict__ efL,
                                                  float* __restrict__ out_zq,
                                                  float* __restrict__ out_idx,
                                                  unsigned int* __restrict__ counts,
                                                  float* __restrict__ sse_part)
{
#pragma clang fp contract(off)
    __shared__ short8 s_zfh[512];            // [2 tt][8 g][32 n]   8 KB
    __shared__ short8 s_zfl[512];            //                     8 KB
    __shared__ float2 s_sel[32 * SEL_STRIDE];// [tile][token] padded 16.25 KB
    __shared__ int    s_bi[64];
    __shared__ float  s_wsse[4];

    const int tid = threadIdx.x;
    const int wv = tid >> 6, lane = tid & 63;
    const int h = lane >> 5, ml = lane & 31;
    const int t0 = blockIdx.x * 64;

    // ---- S: all waves stage; wave wv owns groups {2wv, 2wv+1} ------------
    {
        const float4* zp = (const float4*)(z_e + (size_t)(t0 + lane) * ED);
        const int n = lane & 31, ttl = lane >> 5;
#pragma unroll
        for (int gg = 0; gg < 2; ++gg) {
            const int g = wv * 2 + gg;
            float4 a = zp[2 * g], b = zp[2 * g + 1];
            float v[8] = {a.x, a.y, a.z, a.w, b.x, b.y, b.z, b.w};
            short8 hv, lv;
#pragma unroll
            for (int j = 0; j < 8; ++j) {
                unsigned short hb = f2bf(v[j]);    // bit-identical split
                hv[j] = (short)hb;
                lv[j] = (short)f2bf(v[j] - bf2f(hb));
            }
            s_zfh[(ttl * 8 + g) * 32 + n] = hv;
            s_zfl[(ttl * 8 + g) * 32 + n] = lv;
        }
    }
    __syncthreads();

    // ---- M: score all 32 code tiles (4 groups x 2 tiles/wave) ------------
#pragma unroll
    for (int g = 0; g < 4; ++g) {
        short8 ea[2][4], eb[2][4];                 // A-frags for this group
#pragma unroll
        for (int mt = 0; mt < 2; ++mt) {
            const int ct = g * 8 + wv * 2 + mt;
#pragma unroll
            for (int q = 0; q < 4; ++q) {
                const int idx = (ct * 8 + q * 2 + h) * 32 + ml;
                ea[mt][q] = efH[idx];
                eb[mt][q] = efL[idx];
            }
        }
#pragma unroll
        for (int it = 0; it < 2; ++it) {
            float16 acc0 = {}, acc1 = {};
#pragma unroll
            for (int q = 0; q < 4; ++q) {
                const int idx = (it * 8 + q * 2 + h) * 32 + ml;
                const short8 zh = s_zfh[idx];
                const short8 zl = s_zfl[idx];
                acc0 = __builtin_amdgcn_mfma_f32_32x32x16_bf16(ea[0][q], zh, acc0, 0, 0, 0);
                acc1 = __builtin_amdgcn_mfma_f32_32x32x16_bf16(ea[1][q], zh, acc1, 0, 0, 0);
                acc0 = __builtin_amdgcn_mfma_f32_32x32x16_bf16(ea[0][q], zl, acc0, 0, 0, 0);
                acc1 = __builtin_amdgcn_mfma_f32_32x32x16_bf16(ea[1][q], zl, acc1, 0, 0, 0);
                acc0 = __builtin_amdgcn_mfma_f32_32x32x16_bf16(eb[0][q], zh, acc0, 0, 0, 0);
                acc1 = __builtin_amdgcn_mfma_f32_32x32x16_bf16(eb[1][q], zh, acc1, 0, 0, 0);
            }
#pragma unroll
            for (int mt = 0; mt < 2; ++mt) {
                const float16 acc = mt ? acc1 : acc0;
                // Tree reduce, rg-adjacent, keep-left-on-tie: bit-identical
                // (v1 = max, i1 = mrow of FIRST max in rg order, v2 = exact
                // 2nd-largest via max(min(maxA,maxB), v2A, v2B)).
                float tv1[8], tv2[8];
                int   ti[8];
#pragma unroll
                for (int p = 0; p < 8; ++p) {
                    const float a = acc[2 * p], b = acc[2 * p + 1];
                    const int ia = ((2 * p) & 3) + 8 * ((2 * p) >> 2) + 4 * h;
                    const int ib = ((2 * p + 1) & 3) + 8 * ((2 * p + 1) >> 2) + 4 * h;
                    const bool gt = b > a;
                    tv1[p] = gt ? b : a;
                    ti[p]  = gt ? ib : ia;
                    tv2[p] = gt ? a : b;
                }
#pragma unroll
                for (int s = 4; s >= 1; s >>= 1) {
#pragma unroll
                    for (int p = 0; p < s; ++p) {
                        const float av1 = tv1[2 * p], bv1 = tv1[2 * p + 1];
                        const bool gt = bv1 > av1;
                        const float inner = gt ? av1 : bv1;
                        tv1[p] = gt ? bv1 : av1;
                        ti[p]  = gt ? ti[2 * p + 1] : ti[2 * p];
                        tv2[p] = fmaxf(fmaxf(tv2[2 * p], tv2[2 * p + 1]), inner);
                    }
                }
                float v1 = tv1[0], v2 = tv2[0];
                int i1 = ti[0];
                const float o1 = __shfl_xor(v1, 32);
                const float o2 = __shfl_xor(v2, 32);
                const int   oi = __shfl_xor(i1, 32);
                const float lo = fminf(v1, o1);
                if (o1 > v1) { v1 = o1; i1 = oi; }
                v2 = fmaxf(lo, fmaxf(v2, o2));      // exact 2nd-largest merge
                if (lane < 32) {
                    const unsigned bits = (__float_as_uint(-2.f * v1) & ~31u) | (unsigned)i1;
                    float2 o;
                    o.x = __uint_as_float(bits);    // bit-identical tA
                    o.y = -2.f * v2;                // bit-identical tB
                    s_sel[(g * 8 + wv * 2 + mt) * SEL_STRIDE + it * 32 + lane] = o;
                }
            }
        }
    }

    // ---- E-prefetch: z float4s into regs BEFORE the barrier --------------
    const float4* z4  = (const float4*)z_e + (size_t)t0 * 16;
    float4 zv[4];
#pragma unroll
    for (int p = 0; p < 4; ++p) zv[p] = z4[p * 256 + tid];
    __syncthreads();

    // ---- R: selection, ALL waves, 4 lanes/token --------------------------
    {
        const int tls = tid >> 2;              // token slot 0..63
        const int sub = tid & 3;               // owns tiles sub*8 .. sub*8+7
        const int t = t0 + tls;

        float av[8], bv[8];
        float m = FLT_MAX;
#pragma unroll
        for (int i = 0; i < 8; ++i) {
            const float2 p = s_sel[(sub * 8 + i) * SEL_STRIDE + tls];
            av[i] = p.x; bv[i] = p.y;
            m = fminf(m, av[i]);
        }
        m = fminf(m, __shfl_xor(m, 1));        // exact fminf tree == min32
        m = fminf(m, __shfl_xor(m, 2));
        const float thr = m + EPS;

        unsigned band8 = 0u, full8 = 0u;
        int cand0 = 0, nb = 0;
#pragma unroll
        for (int i = 0; i < 8; ++i) {
            if (av[i] <= thr) {
                if (nb == 0)
                    cand0 = (sub * 8 + i) * 32 + (int)(__float_as_uint(av[i]) & 31u);
                ++nb;
                band8 |= (1u << i);
                if (bv[i] <= thr) full8 |= (1u << i);
            }
        }
        // merge (nb, first-in-ct-order cand0, full-any) across the quad:
        // lo-sub partition wins when nonempty == frozen first-tile order.
        int fullany = (full8 != 0u);
        {
            int nb_o = __shfl_xor(nb, 1);
            int c0_o = __shfl_xor(cand0, 1);
            int fa_o = __shfl_xor(fullany, 1);
            cand0 = ((sub & 1) == 0) ? (nb ? cand0 : c0_o) : (nb_o ? c0_o : cand0);
            nb += nb_o; fullany |= fa_o;
            nb_o = __shfl_xor(nb, 2);
            c0_o = __shfl_xor(cand0, 2);
            fa_o = __shfl_xor(fullany, 2);
            cand0 = ((sub & 2) == 0) ? (nb ? cand0 : c0_o) : (nb_o ? c0_o : cand0);
            nb += nb_o; fullany |= fa_o;
        }

        int bsel;
        if (nb == 1 && !fullany) {
            bsel = cand0;              // unambiguous: band proves exact argmin
        } else {
            // Rare path (quad-uniform branch): each lane rescores its own
            // in-band tiles with the frozen chain; lex merge across quad.
            const float4* zp = (const float4*)(z_e + (size_t)t * ED);
            float zr[ED];
#pragma unroll
            for (int i = 0; i < 16; ++i) {
                const float4 v = zp[i];
                zr[4 * i + 0] = v.x; zr[4 * i + 1] = v.y;
                zr[4 * i + 2] = v.z; zr[4 * i + 3] = v.w;
            }
            // frozen zsq: numpy pairwise n=64, 8 accs strided 8, mul+add
            float r[8];
#pragma unroll
            for (int g2 = 0; g2 < 8; ++g2) {
#pragma unroll
                for (int j = 0; j < 8; ++j) {
                    const float sq = zr[g2 * 8 + j] * zr[g2 * 8 + j];
                    r[j] = g2 ? (r[j] + sq) : sq;
                }
            }
            const float zsq = ((r[0] + r[1]) + (r[2] + r[3])) + ((r[4] + r[5]) + (r[6] + r[7]));
            float best = FLT_MAX;
            int bi = 0;
            unsigned rem = band8;
            while (rem) {
                const int i = __ffs(rem) - 1;
                rem &= rem - 1;
                const int ct = sub * 8 + i;
                if (full8 & (1u << i)) {
                    for (int j = 0; j < 32; ++j) RESCORE(ct * 32 + j);
                } else {
                    RESCORE(ct * 32 + (int)(__float_as_uint(av[i]) & 31u));
                }
            }
#pragma unroll
            for (int d = 1; d <= 2; d <<= 1) {
                const float ob  = __shfl_xor(best, d);
                const int   obi = __shfl_xor(bi, d);
                if (ob < best || (ob == best && obi < bi)) { best = ob; bi = obi; }
            }
            bsel = bi;
        }

        if (sub == 0) {
            s_bi[tls] = bsel;
            out_idx[t] = (float)bsel;
            atomicAdd(&counts[(blockIdx.x & 3) * K_CODES + bsel], 1u);  // sharded
        }
    }
    __syncthreads();

    // ---- E: epilogue, flat-contiguous (thread <-> float4), z pre-loaded --
    float4* o4 = (float4*)out_zq + (size_t)t0 * 16;
    const float4* eq4 = (const float4*)cb;
    float lsse = 0.f;
#pragma unroll
    for (int p = 0; p < 4; ++p) {
        const int f = p * 256 + tid;               // 0..1023 float4s
        const int bq = s_bi[f >> 4];
        const float4 q = eq4[(size_t)bq * 16 + (f & 15)];
        o4[f] = q;
        float dx = q.x - zv[p].x; lsse = fmaf(dx, dx, lsse);
        float dy = q.y - zv[p].y; lsse = fmaf(dy, dy, lsse);
        float dz = q.z - zv[p].z; lsse = fmaf(dz, dz, lsse);
        float dw = q.w - zv[p].w; lsse = fmaf(dw, dw, lsse);
    }
#pragma unroll
    for (int off = 32; off > 0; off >>= 1)
        lsse += __shfl_down(lsse, off, 64);
    if (lane == 0) s_wsse[wv] = lsse;
    __syncthreads();
    if (tid == 0)
        atomicAdd(&sse_part[blockIdx.x & 63],
                  (s_wsse[0] + s_wsse[1]) + (s_wsse[2] + s_wsse[3]));
}

// ---------------------------------------------------------------------------
// final: entropy / losses scalars (sums 4 count shards + 64 SSE partials)
// ---------------------------------------------------------------------------
__global__ __launch_bounds__(1024) void vq_final(const unsigned int* __restrict__ counts,
                                                 const float* __restrict__ sse_part,
                                                 float* __restrict__ out_sc)
{
    __shared__ float red[1024];
    const int i = threadIdx.x;
    const unsigned int cu = counts[i] + counts[i + 1024]
                          + counts[i + 2048] + counts[i + 3072];
    const float c = (float)cu;
    const float p = c / (float)NTOK + 1e-10f;
    red[i] = p * logf(p);
    __syncthreads();
    for (int s = 512; s > 0; s >>= 1) {
        if (i < s) red[i] += red[i + s];
        __syncthreads();
    }
    if (i == 0) {
        const float entropy = -red[0];
        float ssum = 0.f;
        for (int k = 0; k < 64; ++k) ssum += sse_part[k];
        const float cbl = ssum / ((float)NTOK * (float)ED);
        out_sc[0] = cbl;                                   // codebook_loss
        out_sc[1] = 0.25f * cbl;                           // commitment_loss
        out_sc[2] = -0.1f * (entropy / 6.93147180559945f); // entropy_loss
        out_sc[3] = expf(entropy);                         // perplexity
    }
}

// ---------------------------------------------------------------------------
extern "C" void kernel_launch(void* const* d_in, const int* in_sizes, int n_in,
                              void* d_out, int out_size, void* d_ws, size_t ws_size,
                              hipStream_t stream)
{
    const float* z_e = (const float*)d_in[0];
    const float* cb  = (const float*)d_in[1];

    float* out   = (float*)d_out;
    float* o_zq  = out;                              // [131072,64]
    float* o_idx = out + (size_t)NTOK * ED;          // [131072] (as float)
    float* o_sc  = o_idx + NTOK;                     // 4 scalars

    char* ws = (char*)d_ws;
    float*        e_sq     = (float*)(ws);                   // 4 KB
    unsigned int* counts   = (unsigned int*)(ws + 4096);     // 16 KB (4 shards)
    float*        sse_part = (float*)(ws + 20480);           // 256 B
    short8*       efH      = (short8*)(ws + 32768);          // 128 KB
    short8*       efL      = (short8*)(ws + 163840);         // 128 KB (ends 288 KB)

    vq_codes<<<16, 64, 0, stream>>>(cb, e_sq, efH, efL, counts, sse_part);
    vq_main <<<NTOK / 64, 256, 0, stream>>>(z_e, cb, e_sq, efH, efL,
                                            o_zq, o_idx, counts, sse_part);
    vq_final<<<1, 1024, 0, stream>>>(counts, sse_part, o_sc);
}

// Round 11
// 165.693 us; speedup vs baseline: 1.5581x; 1.0103x over previous
//
#include <hip/hip_runtime.h>
#include <float.h>
#include <math.h>

#define K_CODES 1024
#define ED 64
#define NTOK 131072
#define EPS 4e-4f   // flag band; approx-vs-exact bound ~7e-5 -> 6x margin

typedef __attribute__((ext_vector_type(8)))  short short8;   // 8 bf16 (4 VGPRs)
typedef __attribute__((ext_vector_type(16))) float float16;  // MFMA 32x32 acc

// ---------------------------------------------------------------------------
// NUMERICS OF THE EXACT PATH ARE FROZEN (0 flips across all passing rounds):
//  - zsq / e_sq: numpy pairwise_sum n=64 (8 accs strided 8, mul+add no fma,
//    combine ((r0+r1)+(r2+r3))+((r4+r5)+(r6+r7))), contract(off).
//  - dot(z,e): single sequential fmaf chain over d=0..63.
//  - d2 = fmaf(-2,dot,zsq) + e_sq.
//  - argmin: first index wins (lexicographic (value,index) updates).
//
// Round-17 (this file), from round-10 PMC (total 167.4, vq_main 102,
// conflicts 786K->262K residual 2-way=free, VGPR 80) + accounting (~65us
// outside vq_main in vq_codes/vq_final/gaps; accounting closed in the
// 4-kernel era, so this is real kernel time):
//  (a) vq_codes: coalesced restructure. 16 blocks x 256 threads; float4
//      loads thread<->element (coalesced) -> LDS staged rows (stride 68
//      floats, breaks the 64-float bank alias); conversions 4 lanes/code
//      (element-wise f2bf -> bit-identical frags); e_sq computed by ONE
//      thread per code from LDS with the byte-identical frozen chain.
//  (b) vq_final: serial 64-load ssum on thread 0 -> wave shuffle-reduce
//      (scalar outputs already atomic-order-nondeterministic; in-band).
//  (c) vq_main: __launch_bounds__(256,3) -> (256,2). Relaxes the VGPR
//      budget (round-6's spill was arg=4 SHRINKING it to 64; arg=2 grows
//      it) for deeper M-phase scheduling. Revert if VGPR>170 or spills.
// vq_main S/M/R/E logic byte-identical to round-10 (passing).
// ---------------------------------------------------------------------------

static __device__ __forceinline__ unsigned short f2bf(float x) {  // RNE
    unsigned u = __float_as_uint(x);
    u += 0x7fffu + ((u >> 16) & 1u);
    return (unsigned short)(u >> 16);
}
static __device__ __forceinline__ float bf2f(unsigned short h) {
    return __uint_as_float(((unsigned)h) << 16);
}

// ---------------------------------------------------------------------------
// code pre: 16 blocks x 256 threads, 64 codes/block.
//  L: coalesced float4 loads of 64 code rows -> LDS (padded stride 68).
//  C: 4 lanes/code convert groups {2sub, 2sub+1} -> ef frags (bit-identical
//     element-wise f2bf hi/lo).
//  Q: threads 0..63: frozen pairwise e_sq chain per code from LDS.
//  Z: zero counts shards (4096 across the grid) / sse partials.
// ---------------------------------------------------------------------------
__global__ __launch_bounds__(256) void vq_codes(const float* __restrict__ cb,
                                                float* __restrict__ e_sq,
                                                short8* __restrict__ efH,
                                                short8* __restrict__ efL,
                                                unsigned int* __restrict__ counts,
                                                float* __restrict__ sse_part)
{
#pragma clang fp contract(off)
    __shared__ float s_cb[64 * 68];                 // 64 rows, stride 68 fl
    const int tid = threadIdx.x;
    const int k0 = blockIdx.x * 64;                 // first code of block

    // ---- L: coalesced load, 1024 float4s ---------------------------------
    const float4* cb4 = (const float4*)(cb + (size_t)k0 * ED);
#pragma unroll
    for (int p = 0; p < 4; ++p) {
        const int f = p * 256 + tid;                // 0..1023
        const float4 v = cb4[f];
        float4* dst = (float4*)&s_cb[(f >> 4) * 68 + (f & 15) * 4];
        *dst = v;
    }
    __syncthreads();

    // ---- C: convert, 4 lanes/code, 2 groups each --------------------------
    {
        const int c = tid >> 2, sub = tid & 3;      // code-local, group pair
        const int k = k0 + c;
        const int m = k & 31, ct = k >> 5;
#pragma unroll
        for (int gg = 0; gg < 2; ++gg) {
            const int g = sub * 2 + gg;
            const float4 a = *(const float4*)&s_cb[c * 68 + g * 8];
            const float4 b = *(const float4*)&s_cb[c * 68 + g * 8 + 4];
            float v[8] = {a.x, a.y, a.z, a.w, b.x, b.y, b.z, b.w};
            short8 hv, lv;
#pragma unroll
            for (int j = 0; j < 8; ++j) {
                unsigned short hb = f2bf(v[j]);     // bit-identical split
                hv[j] = (short)hb;
                lv[j] = (short)f2bf(v[j] - bf2f(hb));
            }
            efH[(ct * 8 + g) * 32 + m] = hv;
            efL[(ct * 8 + g) * 32 + m] = lv;
        }
    }

    // ---- Q: frozen e_sq, one thread per code ------------------------------
    if (tid < 64) {
        float r[8];
#pragma unroll
        for (int g = 0; g < 8; ++g) {
            const float4 a = *(const float4*)&s_cb[tid * 68 + g * 8];
            const float4 b = *(const float4*)&s_cb[tid * 68 + g * 8 + 4];
            float v[8] = {a.x, a.y, a.z, a.w, b.x, b.y, b.z, b.w};
#pragma unroll
            for (int j = 0; j < 8; ++j) {
                const float sq = v[j] * v[j];       // frozen pairwise e_sq
                r[j] = g ? (r[j] + sq) : sq;
            }
        }
        e_sq[k0 + tid] = ((r[0] + r[1]) + (r[2] + r[3])) + ((r[4] + r[5]) + (r[6] + r[7]));
    }

    // ---- Z: zero counts shards / sse partials -----------------------------
    counts[blockIdx.x * 256 + tid] = 0u;            // 16*256 = 4096 = 4 shards
    if (blockIdx.x == 0 && tid < 64) sse_part[tid] = 0.f;
}

// ---------------------------------------------------------------------------
// Frozen exact rescore of code (cc): single sequential fmaf chain d=0..63,
// d2 = fmaf(-2,dot,zsq) + e_sq; lexicographic (d2, idx) update.
#define RESCORE(cc)                                                          \
    do {                                                                     \
        const int c_ = (cc);                                                 \
        const float4* e4_ = (const float4*)(cb + (size_t)c_ * ED);           \
        float a_ = 0.f;                                                      \
        _Pragma("unroll")                                                    \
        for (int jj_ = 0; jj_ < 16; ++jj_) {                                 \
            const float4 v_ = e4_[jj_];                                      \
            a_ = fmaf(zr[4 * jj_ + 0], v_.x, a_);                            \
            a_ = fmaf(zr[4 * jj_ + 1], v_.y, a_);                            \
            a_ = fmaf(zr[4 * jj_ + 2], v_.z, a_);                            \
            a_ = fmaf(zr[4 * jj_ + 3], v_.w, a_);                            \
        }                                                                    \
        const float d2_ = fmaf(-2.f, a_, zsq) + e_sq[c_];                    \
        if (d2_ < best || (d2_ == best && c_ < bi)) { best = d2_; bi = c_; } \
    } while (0)

#define SEL_STRIDE 65   // padded: bank = (2*tls + 16*sub + 2*i) mod 32

// ---------------------------------------------------------------------------
// fused main: 64 tokens/block, 2048 blocks, 4 waves.
//  S: wave wv stages z frags for groups {2wv,2wv+1}, lane=token.
//  M: wave owns tiles {g*8+wv*2, +1} per group (4 groups, unrolled);
//     tree-reduced bit-identical (max,argmax-first,exact-2nd) -> LDS sel.
//  R: ALL waves, 4 lanes/token (sub = tid&3 owns tiles sub*8..sub*8+7);
//     quad merge via shfl_xor(1,2); rare rescore recomputes frozen zsq.
//  E: coalesced epilogue; z pre-fetched into regs before the R barrier.
// ---------------------------------------------------------------------------
__global__ __launch_bounds__(256, 2) void vq_main(const float* __restrict__ z_e,
                                                  const float* __restrict__ cb,
                                                  const float* __restrict__ e_sq,
                                                  const short8* __restrict__ efH,
                                                  const short8* __restrict__ efL,
                                                  float* __restrict__ out_zq,
                                                  float* __restrict__ out_idx,
                                                  unsigned int* __restrict__ counts,
                                                  float* __restrict__ sse_part)
{
#pragma clang fp contract(off)
    __shared__ short8 s_zfh[512];            // [2 tt][8 g][32 n]   8 KB
    __shared__ short8 s_zfl[512];            //                     8 KB
    __shared__ float2 s_sel[32 * SEL_STRIDE];// [tile][token] padded 16.25 KB
    __shared__ int    s_bi[64];
    __shared__ float  s_wsse[4];

    const int tid = threadIdx.x;
    const int wv = tid >> 6, lane = tid & 63;
    const int h = lane >> 5, ml = lane & 31;
    const int t0 = blockIdx.x * 64;

    // ---- S: all waves stage; wave wv owns groups {2wv, 2wv+1} ------------
    {
        const float4* zp = (const float4*)(z_e + (size_t)(t0 + lane) * ED);
        const int n = lane & 31, ttl = lane >> 5;
#pragma unroll
        for (int gg = 0; gg < 2; ++gg) {
            const int g = wv * 2 + gg;
            float4 a = zp[2 * g], b = zp[2 * g + 1];
            float v[8] = {a.x, a.y, a.z, a.w, b.x, b.y, b.z, b.w};
            short8 hv, lv;
#pragma unroll
            for (int j = 0; j < 8; ++j) {
                unsigned short hb = f2bf(v[j]);    // bit-identical split
                hv[j] = (short)hb;
                lv[j] = (short)f2bf(v[j] - bf2f(hb));
            }
            s_zfh[(ttl * 8 + g) * 32 + n] = hv;
            s_zfl[(ttl * 8 + g) * 32 + n] = lv;
        }
    }
    __syncthreads();

    // ---- M: score all 32 code tiles (4 groups x 2 tiles/wave) ------------
#pragma unroll
    for (int g = 0; g < 4; ++g) {
        short8 ea[2][4], eb[2][4];                 // A-frags for this group
#pragma unroll
        for (int mt = 0; mt < 2; ++mt) {
            const int ct = g * 8 + wv * 2 + mt;
#pragma unroll
            for (int q = 0; q < 4; ++q) {
                const int idx = (ct * 8 + q * 2 + h) * 32 + ml;
                ea[mt][q] = efH[idx];
                eb[mt][q] = efL[idx];
            }
        }
#pragma unroll
        for (int it = 0; it < 2; ++it) {
            float16 acc0 = {}, acc1 = {};
#pragma unroll
            for (int q = 0; q < 4; ++q) {
                const int idx = (it * 8 + q * 2 + h) * 32 + ml;
                const short8 zh = s_zfh[idx];
                const short8 zl = s_zfl[idx];
                acc0 = __builtin_amdgcn_mfma_f32_32x32x16_bf16(ea[0][q], zh, acc0, 0, 0, 0);
                acc1 = __builtin_amdgcn_mfma_f32_32x32x16_bf16(ea[1][q], zh, acc1, 0, 0, 0);
                acc0 = __builtin_amdgcn_mfma_f32_32x32x16_bf16(ea[0][q], zl, acc0, 0, 0, 0);
                acc1 = __builtin_amdgcn_mfma_f32_32x32x16_bf16(ea[1][q], zl, acc1, 0, 0, 0);
                acc0 = __builtin_amdgcn_mfma_f32_32x32x16_bf16(eb[0][q], zh, acc0, 0, 0, 0);
                acc1 = __builtin_amdgcn_mfma_f32_32x32x16_bf16(eb[1][q], zh, acc1, 0, 0, 0);
            }
#pragma unroll
            for (int mt = 0; mt < 2; ++mt) {
                const float16 acc = mt ? acc1 : acc0;
                // Tree reduce, rg-adjacent, keep-left-on-tie: bit-identical
                // (v1 = max, i1 = mrow of FIRST max in rg order, v2 = exact
                // 2nd-largest via max(min(maxA,maxB), v2A, v2B)).
                float tv1[8], tv2[8];
                int   ti[8];
#pragma unroll
                for (int p = 0; p < 8; ++p) {
                    const float a = acc[2 * p], b = acc[2 * p + 1];
                    const int ia = ((2 * p) & 3) + 8 * ((2 * p) >> 2) + 4 * h;
                    const int ib = ((2 * p + 1) & 3) + 8 * ((2 * p + 1) >> 2) + 4 * h;
                    const bool gt = b > a;
                    tv1[p] = gt ? b : a;
                    ti[p]  = gt ? ib : ia;
                    tv2[p] = gt ? a : b;
                }
#pragma unroll
                for (int s = 4; s >= 1; s >>= 1) {
#pragma unroll
                    for (int p = 0; p < s; ++p) {
                        const float av1 = tv1[2 * p], bv1 = tv1[2 * p + 1];
                        const bool gt = bv1 > av1;
                        const float inner = gt ? av1 : bv1;
                        tv1[p] = gt ? bv1 : av1;
                        ti[p]  = gt ? ti[2 * p + 1] : ti[2 * p];
                        tv2[p] = fmaxf(fmaxf(tv2[2 * p], tv2[2 * p + 1]), inner);
                    }
                }
                float v1 = tv1[0], v2 = tv2[0];
                int i1 = ti[0];
                const float o1 = __shfl_xor(v1, 32);
                const float o2 = __shfl_xor(v2, 32);
                const int   oi = __shfl_xor(i1, 32);
                const float lo = fminf(v1, o1);
                if (o1 > v1) { v1 = o1; i1 = oi; }
                v2 = fmaxf(lo, fmaxf(v2, o2));      // exact 2nd-largest merge
                if (lane < 32) {
                    const unsigned bits = (__float_as_uint(-2.f * v1) & ~31u) | (unsigned)i1;
                    float2 o;
                    o.x = __uint_as_float(bits);    // bit-identical tA
                    o.y = -2.f * v2;                // bit-identical tB
                    s_sel[(g * 8 + wv * 2 + mt) * SEL_STRIDE + it * 32 + lane] = o;
                }
            }
        }
    }

    // ---- E-prefetch: z float4s into regs BEFORE the barrier --------------
    const float4* z4  = (const float4*)z_e + (size_t)t0 * 16;
    float4 zv[4];
#pragma unroll
    for (int p = 0; p < 4; ++p) zv[p] = z4[p * 256 + tid];
    __syncthreads();

    // ---- R: selection, ALL waves, 4 lanes/token --------------------------
    {
        const int tls = tid >> 2;              // token slot 0..63
        const int sub = tid & 3;               // owns tiles sub*8 .. sub*8+7
        const int t = t0 + tls;

        float av[8], bv[8];
        float m = FLT_MAX;
#pragma unroll
        for (int i = 0; i < 8; ++i) {
            const float2 p = s_sel[(sub * 8 + i) * SEL_STRIDE + tls];
            av[i] = p.x; bv[i] = p.y;
            m = fminf(m, av[i]);
        }
        m = fminf(m, __shfl_xor(m, 1));        // exact fminf tree == min32
        m = fminf(m, __shfl_xor(m, 2));
        const float thr = m + EPS;

        unsigned band8 = 0u, full8 = 0u;
        int cand0 = 0, nb = 0;
#pragma unroll
        for (int i = 0; i < 8; ++i) {
            if (av[i] <= thr) {
                if (nb == 0)
                    cand0 = (sub * 8 + i) * 32 + (int)(__float_as_uint(av[i]) & 31u);
                ++nb;
                band8 |= (1u << i);
                if (bv[i] <= thr) full8 |= (1u << i);
            }
        }
        // merge (nb, first-in-ct-order cand0, full-any) across the quad:
        // lo-sub partition wins when nonempty == frozen first-tile order.
        int fullany = (full8 != 0u);
        {
            int nb_o = __shfl_xor(nb, 1);
            int c0_o = __shfl_xor(cand0, 1);
            int fa_o = __shfl_xor(fullany, 1);
            cand0 = ((sub & 1) == 0) ? (nb ? cand0 : c0_o) : (nb_o ? c0_o : cand0);
            nb += nb_o; fullany |= fa_o;
            nb_o = __shfl_xor(nb, 2);
            c0_o = __shfl_xor(cand0, 2);
            fa_o = __shfl_xor(fullany, 2);
            cand0 = ((sub & 2) == 0) ? (nb ? cand0 : c0_o) : (nb_o ? c0_o : cand0);
            nb += nb_o; fullany |= fa_o;
        }

        int bsel;
        if (nb == 1 && !fullany) {
            bsel = cand0;              // unambiguous: band proves exact argmin
        } else {
            // Rare path (quad-uniform branch): each lane rescores its own
            // in-band tiles with the frozen chain; lex merge across quad.
            const float4* zp = (const float4*)(z_e + (size_t)t * ED);
            float zr[ED];
#pragma unroll
            for (int i = 0; i < 16; ++i) {
                const float4 v = zp[i];
                zr[4 * i + 0] = v.x; zr[4 * i + 1] = v.y;
                zr[4 * i + 2] = v.z; zr[4 * i + 3] = v.w;
            }
            // frozen zsq: numpy pairwise n=64, 8 accs strided 8, mul+add
            float r[8];
#pragma unroll
            for (int g2 = 0; g2 < 8; ++g2) {
#pragma unroll
                for (int j = 0; j < 8; ++j) {
                    const float sq = zr[g2 * 8 + j] * zr[g2 * 8 + j];
                    r[j] = g2 ? (r[j] + sq) : sq;
                }
            }
            const float zsq = ((r[0] + r[1]) + (r[2] + r[3])) + ((r[4] + r[5]) + (r[6] + r[7]));
            float best = FLT_MAX;
            int bi = 0;
            unsigned rem = band8;
            while (rem) {
                const int i = __ffs(rem) - 1;
                rem &= rem - 1;
                const int ct = sub * 8 + i;
                if (full8 & (1u << i)) {
                    for (int j = 0; j < 32; ++j) RESCORE(ct * 32 + j);
                } else {
                    RESCORE(ct * 32 + (int)(__float_as_uint(av[i]) & 31u));
                }
            }
#pragma unroll
            for (int d = 1; d <= 2; d <<= 1) {
                const float ob  = __shfl_xor(best, d);
                const int   obi = __shfl_xor(bi, d);
                if (ob < best || (ob == best && obi < bi)) { best = ob; bi = obi; }
            }
            bsel = bi;
        }

        if (sub == 0) {
            s_bi[tls] = bsel;
            out_idx[t] = (float)bsel;
            atomicAdd(&counts[(blockIdx.x & 3) * K_CODES + bsel], 1u);  // sharded
        }
    }
    __syncthreads();

    // ---- E: epilogue, flat-contiguous (thread <-> float4), z pre-loaded --
    float4* o4 = (float4*)out_zq + (size_t)t0 * 16;
    const float4* eq4 = (const float4*)cb;
    float lsse = 0.f;
#pragma unroll
    for (int p = 0; p < 4; ++p) {
        const int f = p * 256 + tid;               // 0..1023 float4s
        const int bq = s_bi[f >> 4];
        const float4 q = eq4[(size_t)bq * 16 + (f & 15)];
        o4[f] = q;
        float dx = q.x - zv[p].x; lsse = fmaf(dx, dx, lsse);
        float dy = q.y - zv[p].y; lsse = fmaf(dy, dy, lsse);
        float dz = q.z - zv[p].z; lsse = fmaf(dz, dz, lsse);
        float dw = q.w - zv[p].w; lsse = fmaf(dw, dw, lsse);
    }
#pragma unroll
    for (int off = 32; off > 0; off >>= 1)
        lsse += __shfl_down(lsse, off, 64);
    if (lane == 0) s_wsse[wv] = lsse;
    __syncthreads();
    if (tid == 0)
        atomicAdd(&sse_part[blockIdx.x & 63],
                  (s_wsse[0] + s_wsse[1]) + (s_wsse[2] + s_wsse[3]));
}

// ---------------------------------------------------------------------------
// final: entropy / losses scalars (sums 4 count shards + 64 SSE partials;
// SSE partial sum wave-parallel -- accumulation order already atomic-
// nondeterministic, so only last-bit scalar wiggle, well in-band).
// ---------------------------------------------------------------------------
__global__ __launch_bounds__(1024) void vq_final(const unsigned int* __restrict__ counts,
                                                 const float* __restrict__ sse_part,
                                                 float* __restrict__ out_sc)
{
    __shared__ float red[1024];
    __shared__ float s_ssum;
    const int i = threadIdx.x;
    const unsigned int cu = counts[i] + counts[i + 1024]
                          + counts[i + 2048] + counts[i + 3072];
    const float c = (float)cu;
    const float p = c / (float)NTOK + 1e-10f;
    red[i] = p * logf(p);
    if (i < 64) {
        float s = sse_part[i];
#pragma unroll
        for (int off = 32; off > 0; off >>= 1)
            s += __shfl_down(s, off, 64);
        if (i == 0) s_ssum = s;
    }
    __syncthreads();
    for (int s = 512; s > 0; s >>= 1) {
        if (i < s) red[i] += red[i + s];
        __syncthreads();
    }
    if (i == 0) {
        const float entropy = -red[0];
        const float cbl = s_ssum / ((float)NTOK * (float)ED);
        out_sc[0] = cbl;                                   // codebook_loss
        out_sc[1] = 0.25f * cbl;                           // commitment_loss
        out_sc[2] = -0.1f * (entropy / 6.93147180559945f); // entropy_loss
        out_sc[3] = expf(entropy);                         // perplexity
    }
}

// ---------------------------------------------------------------------------
extern "C" void kernel_launch(void* const* d_in, const int* in_sizes, int n_in,
                              void* d_out, int out_size, void* d_ws, size_t ws_size,
                              hipStream_t stream)
{
    const float* z_e = (const float*)d_in[0];
    const float* cb  = (const float*)d_in[1];

    float* out   = (float*)d_out;
    float* o_zq  = out;                              // [131072,64]
    float* o_idx = out + (size_t)NTOK * ED;          // [131072] (as float)
    float* o_sc  = o_idx + NTOK;                     // 4 scalars

    char* ws = (char*)d_ws;
    float*        e_sq     = (float*)(ws);                   // 4 KB
    unsigned int* counts   = (unsigned int*)(ws + 4096);     // 16 KB (4 shards)
    float*        sse_part = (float*)(ws + 20480);           // 256 B
    short8*       efH      = (short8*)(ws + 32768);          // 128 KB
    short8*       efL      = (short8*)(ws + 163840);         // 128 KB (ends 288 KB)

    vq_codes<<<16, 256, 0, stream>>>(cb, e_sq, efH, efL, counts, sse_part);
    vq_main <<<NTOK / 64, 256, 0, stream>>>(z_e, cb, e_sq, efH, efL,
                                            o_zq, o_idx, counts, sse_part);
    vq_final<<<1, 1024, 0, stream>>>(counts, sse_part, o_sc);
}